// Round 1
// baseline (393.156 us; speedup 1.0000x reference)
//
#include <hip/hip_runtime.h>
#include <cstdint>

constexpr int Sd = 1024;
constexpr int Td = 48;
constexpr int NTAG = 45;    // normal tags 0..44
constexpr int START_ = 45;
constexpr int STOP_ = 46;

__launch_bounds__(64)
__global__ void crf_fused(const float* __restrict__ feats,
                          const float* __restrict__ masks,
                          const int* __restrict__ tags,
                          const float* __restrict__ trans,
                          float* __restrict__ out)
{
    __shared__ float tl[Td * Td];
    const int b = blockIdx.x;
    const int lane = threadIdx.x;

    // stage transitions (9 KiB) into LDS
    for (int i = lane; i < Td * Td; i += 64) tl[i] = trans[i];
    __syncthreads();

    const size_t bS = (size_t)b * Sd;

    // ---- length from prefix mask ----
    float c = 0.f;
    for (int t = lane; t < Sd; t += 64) c += masks[bS + t];
#pragma unroll
    for (int off = 32; off; off >>= 1) c += __shfl_xor(c, off);
    int len = (int)(c + 0.5f);
    if (len < 1) len = 1;

    // ---- gold (score_sentence), lanes parallel over t ----
    float g = 0.f;
    for (int t = lane; t < len; t += 64) {
        const int tag  = tags[bS + t];
        const int prev = (t == 0) ? START_ : tags[bS + t - 1];
        g += feats[(bS + t) * Td + tag] + tl[tag * Td + prev];
    }
#pragma unroll
    for (int off = 32; off; off >>= 1) g += __shfl_xor(g, off);
    g += tl[STOP_ * Td + tags[bS + len - 1]];   // transitions[STOP, last_tag]

    // ---- E = exp(trans) rows in registers; zero START/STOP/PAD rows ----
    float E[Td];
    const bool zrow = (lane >= NTAG);           // rows 45..63 zeroed (sinks / padding)
#pragma unroll
    for (int j = 0; j < Td; ++j)
        E[j] = zrow ? 0.f : __expf(tl[lane * Td + j]);
    const float Estop = (lane < Td) ? __expf(tl[STOP_ * Td + lane]) : 0.f;

    const float* frow = feats + bS * Td;
    const int lidx = (lane < Td) ? lane : 0;

    // ---- step 0 peeled: v_i = exp(emit0_i) * E[i][START] ----
    float v = __expf(frow[lidx]) * E[START_];
    int logacc = 0;
    {
        const float v0 = __shfl(v, 0);
        const int k = (int)((__float_as_uint(v0) >> 23) & 0xFFu) - 127;
        v *= __uint_as_float((uint32_t)(127 - k) << 23);
        logacc += k;
    }

    // one exp-domain step: v <- renorm( exp(fv) * (E . readlane-broadcast(v)) )
    auto crf_step = [&](float fv) {
        const float e = __expf(fv);
        float a0 = 0.f, a1 = 0.f, a2 = 0.f, a3 = 0.f, a4 = 0.f;
#pragma unroll
        for (int j = 0; j < NTAG; j += 5) {
            a0 = fmaf(E[j + 0], __shfl(v, j + 0), a0);
            a1 = fmaf(E[j + 1], __shfl(v, j + 1), a1);
            a2 = fmaf(E[j + 2], __shfl(v, j + 2), a2);
            a3 = fmaf(E[j + 3], __shfl(v, j + 3), a3);
            a4 = fmaf(E[j + 4], __shfl(v, j + 4), a4);
        }
        float vr = (((a0 + a1) + (a2 + a3)) + a4) * e;
        // exact power-of-2 renorm anchored on lane 0 (tag 0: bounded vs max)
        const float v0 = __shfl(vr, 0);
        const int k = (int)((__float_as_uint(v0) >> 23) & 0xFFu) - 127;
        vr *= __uint_as_float((uint32_t)(127 - k) << 23);
        logacc += k;
        v = vr;
    };

    // ---- software-pipelined main loop, prefetch depth 4 ----
    float pf0, pf1, pf2, pf3;
    {
        const int i0 = 1 < len ? 1 : 0, i1 = 2 < len ? 2 : 0;
        const int i2 = 3 < len ? 3 : 0, i3 = 4 < len ? 4 : 0;
        pf0 = frow[(size_t)i0 * Td + lidx];
        pf1 = frow[(size_t)i1 * Td + lidx];
        pf2 = frow[(size_t)i2 * Td + lidx];
        pf3 = frow[(size_t)i3 * Td + lidx];
    }

    int t = 1;
    while (t + 4 <= len) {
        {
            crf_step(pf0);
            const int tn = t + 4; const int idx = tn < len ? tn : 0;
            pf0 = frow[(size_t)idx * Td + lidx];
        }
        {
            crf_step(pf1);
            const int tn = t + 5; const int idx = tn < len ? tn : 0;
            pf1 = frow[(size_t)idx * Td + lidx];
        }
        {
            crf_step(pf2);
            const int tn = t + 6; const int idx = tn < len ? tn : 0;
            pf2 = frow[(size_t)idx * Td + lidx];
        }
        {
            crf_step(pf3);
            const int tn = t + 7; const int idx = tn < len ? tn : 0;
            pf3 = frow[(size_t)idx * Td + lidx];
        }
        t += 4;
    }
    // tail (<=3 steps), static prefetch-register indices
    if (t < len) { crf_step(pf0); ++t; }
    if (t < len) { crf_step(pf1); ++t; }
    if (t < len) { crf_step(pf2); ++t; }

    // ---- final: forward = logacc*ln2 + log( sum_i v_i * exp(trans[STOP,i]) ) ----
    float fs = v * Estop;
#pragma unroll
    for (int off = 32; off; off >>= 1) fs += __shfl_xor(fs, off);
    const float forward = (float)logacc * 0.6931471805599453f + __logf(fs);

    if (lane == 0) out[b] = forward - g;
}

extern "C" void kernel_launch(void* const* d_in, const int* in_sizes, int n_in,
                              void* d_out, int out_size, void* d_ws, size_t ws_size,
                              hipStream_t stream) {
    const float* feats = (const float*)d_in[0];
    const float* masks = (const float*)d_in[1];
    const int*   tags  = (const int*)d_in[2];
    const float* trans = (const float*)d_in[3];
    float* outp = (float*)d_out;

    const int Bn = in_sizes[1] / Sd;   // B = 512
    crf_fused<<<dim3(Bn), dim3(64), 0, stream>>>(feats, masks, tags, trans, outp);
}

// Round 2
// 307.973 us; speedup vs baseline: 1.2766x; 1.2766x over previous
//
#include <hip/hip_runtime.h>
#include <cstdint>

constexpr int Sd = 1024;
constexpr int Td = 48;
constexpr int NTAG = 45;    // normal tags 0..44
constexpr int START_ = 45;
constexpr int STOP_ = 46;

typedef float v2f __attribute__((ext_vector_type(2)));
typedef float v4f __attribute__((ext_vector_type(4)));

constexpr int CH_A = 0;
constexpr int CH_B = 1;

// One exp-domain recurrence step for chain X:
//   tot = E . r          (r = broadcast copy of previous v, via LDS b128 reads)
//   k   = exponent(r[0]) (late renorm anchor, uniform across lanes)
//   vX  = tot * exp(PF) * 2^-k     (if ACT, else frozen)
//   write vX to LDS, re-read 12 x float4 broadcast for next step
#define CRF_STEP(X, PF, ACT) do {                                              \
    v2f a0_ = {0.f,0.f}, a1_ = {0.f,0.f}, a2_ = {0.f,0.f}, a3_ = {0.f,0.f};    \
    _Pragma("unroll")                                                          \
    for (int q_ = 0; q_ < 12; q_ += 2) {                                       \
        v2f lo0_ = { r##X[q_].x,   r##X[q_].y };                               \
        v2f hi0_ = { r##X[q_].z,   r##X[q_].w };                               \
        v2f lo1_ = { r##X[q_+1].x, r##X[q_+1].y };                             \
        v2f hi1_ = { r##X[q_+1].z, r##X[q_+1].w };                             \
        a0_ = __builtin_elementwise_fma(E2[2*q_],   lo0_, a0_);                \
        a1_ = __builtin_elementwise_fma(E2[2*q_+1], hi0_, a1_);                \
        a2_ = __builtin_elementwise_fma(E2[2*q_+2], lo1_, a2_);                \
        a3_ = __builtin_elementwise_fma(E2[2*q_+3], hi1_, a3_);                \
    }                                                                          \
    v2f s_ = (a0_ + a1_) + (a2_ + a3_);                                        \
    float tot_ = s_.x + s_.y;                                                  \
    int k_ = (int)((__float_as_uint(r##X[0].x) >> 23) & 0xFFu) - 127;          \
    float sc_ = __uint_as_float((uint32_t)(127 - k_) << 23);                   \
    float vn_ = tot_ * (__expf(PF) * sc_);                                     \
    v##X = (ACT) ? vn_ : v##X;                                                 \
    L##X += (ACT) ? k_ : 0;                                                    \
    if (lane < Td) vls[CH_##X][lane] = v##X;                                   \
    asm volatile("" ::: "memory"); /* keep reads after the write */           \
    _Pragma("unroll")                                                          \
    for (int q_ = 0; q_ < 12; ++q_)                                            \
        r##X[q_] = ((const v4f*)vls[CH_##X])[q_];                              \
} while (0)

__launch_bounds__(64)
__global__ void crf_fused2(const float* __restrict__ feats,
                           const float* __restrict__ masks,
                           const int* __restrict__ tags,
                           const float* __restrict__ trans,
                           float* __restrict__ out)
{
    __shared__ float tl[Td * Td];
    __shared__ __align__(16) float vls[2][Td];

    const int lane = threadIdx.x;
    const int bA = blockIdx.x * 2;
    const int bB = bA + 1;

    for (int i = lane; i < Td * Td; i += 64) tl[i] = trans[i];
    __syncthreads();

    const size_t bSA = (size_t)bA * Sd;
    const size_t bSB = (size_t)bB * Sd;

    // ---- lengths from prefix masks ----
    auto get_len = [&](size_t bS) {
        float c = 0.f;
        for (int t = lane; t < Sd; t += 64) c += masks[bS + t];
#pragma unroll
        for (int off = 32; off; off >>= 1) c += __shfl_xor(c, off);
        int len = (int)(c + 0.5f);
        return len < 1 ? 1 : len;
    };
    const int lenA = get_len(bSA);
    const int lenB = get_len(bSB);

    // ---- gold scores ----
    auto get_gold = [&](size_t bS, int len) {
        float g = 0.f;
        for (int t = lane; t < len; t += 64) {
            const int tag  = tags[bS + t];
            const int prev = (t == 0) ? START_ : tags[bS + t - 1];
            g += feats[(bS + t) * Td + tag] + tl[tag * Td + prev];
        }
#pragma unroll
        for (int off = 32; off; off >>= 1) g += __shfl_xor(g, off);
        g += tl[STOP_ * Td + tags[bS + len - 1]];
        return g;
    };
    const float gA = get_gold(bSA, lenA);
    const float gB = get_gold(bSB, lenB);

    // ---- E row per lane (shared by both chains), packed as 24 x float2 ----
    v2f E2[24];
    const bool zrow = (lane >= NTAG);      // START/STOP/PAD rows are sinks
#pragma unroll
    for (int q = 0; q < 24; ++q) {
        E2[q].x = zrow ? 0.f : __expf(tl[lane * Td + 2*q]);
        E2[q].y = zrow ? 0.f : __expf(tl[lane * Td + 2*q + 1]);
    }
    const float Estart = E2[22].y;         // E[lane][START_], START_ = 45 = 2*22+1

    const int lidx = (lane < Td) ? lane : 0;
    const float* frowA = feats + bSA * Td;
    const float* frowB = feats + bSB * Td;

    // ---- peeled step 0: v_i = exp(emit0_i) * E[i][START] (no renorm yet) ----
    float vA = __expf(frowA[lidx]) * Estart;
    float vB = __expf(frowB[lidx]) * Estart;
    int LA = 0, LB = 0;
    if (lane < Td) { vls[CH_A][lane] = vA; vls[CH_B][lane] = vB; }
    asm volatile("" ::: "memory");
    v4f rA[12], rB[12];
#pragma unroll
    for (int q = 0; q < 12; ++q) {
        rA[q] = ((const v4f*)vls[CH_A])[q];
        rB[q] = ((const v4f*)vls[CH_B])[q];
    }

    // ---- emission prefetch, depth 4 per chain ----
    float pf0A, pf1A, pf2A, pf3A, pf0B, pf1B, pf2B, pf3B;
    {
        int i;
        i = (1 < lenA) ? 1 : 0; pf0A = frowA[(size_t)i * Td + lidx];
        i = (2 < lenA) ? 2 : 0; pf1A = frowA[(size_t)i * Td + lidx];
        i = (3 < lenA) ? 3 : 0; pf2A = frowA[(size_t)i * Td + lidx];
        i = (4 < lenA) ? 4 : 0; pf3A = frowA[(size_t)i * Td + lidx];
        i = (1 < lenB) ? 1 : 0; pf0B = frowB[(size_t)i * Td + lidx];
        i = (2 < lenB) ? 2 : 0; pf1B = frowB[(size_t)i * Td + lidx];
        i = (3 < lenB) ? 3 : 0; pf2B = frowB[(size_t)i * Td + lidx];
        i = (4 < lenB) ? 4 : 0; pf3B = frowB[(size_t)i * Td + lidx];
    }

    const int maxlen = lenA > lenB ? lenA : lenB;
    int t = 1;
    while (t + 4 <= maxlen) {
        {
            const bool aA = (t < lenA), aB = (t < lenB);
            CRF_STEP(A, pf0A, aA);
            CRF_STEP(B, pf0B, aB);
            const int tn = t + 4;
            pf0A = frowA[(size_t)(tn < lenA ? tn : 0) * Td + lidx];
            pf0B = frowB[(size_t)(tn < lenB ? tn : 0) * Td + lidx];
        }
        {
            const bool aA = (t + 1 < lenA), aB = (t + 1 < lenB);
            CRF_STEP(A, pf1A, aA);
            CRF_STEP(B, pf1B, aB);
            const int tn = t + 5;
            pf1A = frowA[(size_t)(tn < lenA ? tn : 0) * Td + lidx];
            pf1B = frowB[(size_t)(tn < lenB ? tn : 0) * Td + lidx];
        }
        {
            const bool aA = (t + 2 < lenA), aB = (t + 2 < lenB);
            CRF_STEP(A, pf2A, aA);
            CRF_STEP(B, pf2B, aB);
            const int tn = t + 6;
            pf2A = frowA[(size_t)(tn < lenA ? tn : 0) * Td + lidx];
            pf2B = frowB[(size_t)(tn < lenB ? tn : 0) * Td + lidx];
        }
        {
            const bool aA = (t + 3 < lenA), aB = (t + 3 < lenB);
            CRF_STEP(A, pf3A, aA);
            CRF_STEP(B, pf3B, aB);
            const int tn = t + 7;
            pf3A = frowA[(size_t)(tn < lenA ? tn : 0) * Td + lidx];
            pf3B = frowB[(size_t)(tn < lenB ? tn : 0) * Td + lidx];
        }
        t += 4;
    }
    if (t < maxlen) { const bool aA = t < lenA, aB = t < lenB; CRF_STEP(A, pf0A, aA); CRF_STEP(B, pf0B, aB); ++t; }
    if (t < maxlen) { const bool aA = t < lenA, aB = t < lenB; CRF_STEP(A, pf1A, aA); CRF_STEP(B, pf1B, aB); ++t; }
    if (t < maxlen) { const bool aA = t < lenA, aB = t < lenB; CRF_STEP(A, pf2A, aA); CRF_STEP(B, pf2B, aB); ++t; }

    // ---- final: every lane holds the full final v (rA/rB) -> local dot with Estop ----
    float fsA = 0.f, fsB = 0.f;
#pragma unroll
    for (int q = 0; q < 12; ++q) {
        v4f es;
        es.x = __expf(tl[STOP_ * Td + 4*q + 0]);
        es.y = __expf(tl[STOP_ * Td + 4*q + 1]);
        es.z = __expf(tl[STOP_ * Td + 4*q + 2]);
        es.w = __expf(tl[STOP_ * Td + 4*q + 3]);
        fsA += rA[q].x*es.x + rA[q].y*es.y + rA[q].z*es.z + rA[q].w*es.w;
        fsB += rB[q].x*es.x + rB[q].y*es.y + rB[q].z*es.z + rB[q].w*es.w;
    }

    if (lane == 0) {
        const float ln2 = 0.6931471805599453f;
        out[bA] = (float)LA * ln2 + __logf(fsA) - gA;
        out[bB] = (float)LB * ln2 + __logf(fsB) - gB;
    }
}

extern "C" void kernel_launch(void* const* d_in, const int* in_sizes, int n_in,
                              void* d_out, int out_size, void* d_ws, size_t ws_size,
                              hipStream_t stream) {
    const float* feats = (const float*)d_in[0];
    const float* masks = (const float*)d_in[1];
    const int*   tags  = (const int*)d_in[2];
    const float* trans = (const float*)d_in[3];
    float* outp = (float*)d_out;

    const int Bn = in_sizes[1] / Sd;     // B = 512
    crf_fused2<<<dim3(Bn / 2), dim3(64), 0, stream>>>(feats, masks, tags, trans, outp);
}

// Round 3
// 255.515 us; speedup vs baseline: 1.5387x; 1.2053x over previous
//
#include <hip/hip_runtime.h>
#include <cstdint>

constexpr int Sd = 1024;
constexpr int Td = 48;
constexpr int NTAG = 45;    // normal tags 0..44
constexpr int START_ = 45;
constexpr int STOP_ = 46;

typedef float v2f __attribute__((ext_vector_type(2)));
typedef float v4f __attribute__((ext_vector_type(4)));

// One superstep = one forward step (chain F, matrix E) + one backward step
// (chain U, matrix E^T), sharing a single LDS fence. Skeleton per chain:
//   tot = Mrow . r        (r = broadcast of last written vector)
//   k   = exponent(r[0])  (exact power-of-2 renorm, uniform)
//   w   = tot * exp(PF) * 2^-k   (written if active; frozen otherwise)
// Backward additionally captures uFin = tot * 2^-k (scale-consistent with LB).
#define SUPERSTEP(PFF, PFU, AF, AU) do {                                       \
    v2f fa0={0.f,0.f},fa1={0.f,0.f},fa2={0.f,0.f},fa3={0.f,0.f};               \
    v2f ua0={0.f,0.f},ua1={0.f,0.f},ua2={0.f,0.f},ua3={0.f,0.f};               \
    _Pragma("unroll")                                                          \
    for (int q_ = 0; q_ < 12; q_ += 2) {                                       \
        v2f flo0={rF[q_].x,rF[q_].y},   fhi0={rF[q_].z,rF[q_].w};              \
        v2f flo1={rF[q_+1].x,rF[q_+1].y}, fhi1={rF[q_+1].z,rF[q_+1].w};        \
        fa0=__builtin_elementwise_fma(E2[2*q_],  flo0,fa0);                    \
        fa1=__builtin_elementwise_fma(E2[2*q_+1],fhi0,fa1);                    \
        fa2=__builtin_elementwise_fma(E2[2*q_+2],flo1,fa2);                    \
        fa3=__builtin_elementwise_fma(E2[2*q_+3],fhi1,fa3);                    \
        v2f ulo0={rU[q_].x,rU[q_].y},   uhi0={rU[q_].z,rU[q_].w};              \
        v2f ulo1={rU[q_+1].x,rU[q_+1].y}, uhi1={rU[q_+1].z,rU[q_+1].w};        \
        ua0=__builtin_elementwise_fma(ET2[2*q_],  ulo0,ua0);                   \
        ua1=__builtin_elementwise_fma(ET2[2*q_+1],uhi0,ua1);                   \
        ua2=__builtin_elementwise_fma(ET2[2*q_+2],ulo1,ua2);                   \
        ua3=__builtin_elementwise_fma(ET2[2*q_+3],uhi1,ua3);                   \
    }                                                                          \
    v2f fs_=(fa0+fa1)+(fa2+fa3); float totF_=fs_.x+fs_.y;                      \
    v2f us_=(ua0+ua1)+(ua2+ua3); float totU_=us_.x+us_.y;                      \
    int kF_=(int)((__float_as_uint(rF[0].x)>>23)&0xFFu)-127;                   \
    int kU_=(int)((__float_as_uint(rU[0].x)>>23)&0xFFu)-127;                   \
    float scF_=__uint_as_float((uint32_t)(127-kF_)<<23);                       \
    float scU_=__uint_as_float((uint32_t)(127-kU_)<<23);                       \
    float wF_=totF_*(__expf(PFF)*scF_);                                        \
    float wU_=totU_*(__expf(PFU)*scU_);                                        \
    vF = (AF) ? wF_ : vF;   LF += (AF) ? kF_ : 0;                              \
    uW = (AU) ? wU_ : uW;   LB += (AU) ? kU_ : 0;                              \
    uFin = (AU) ? totU_*scU_ : uFin;                                           \
    if (vlane) { vls[0][lane]=vF; vls[1][lane]=uW; }                           \
    asm volatile("" ::: "memory");                                             \
    _Pragma("unroll")                                                          \
    for (int q_ = 0; q_ < 12; ++q_) {                                          \
        rF[q_]=((const v4f*)vls[0])[q_];                                       \
        rU[q_]=((const v4f*)vls[1])[q_];                                       \
    }                                                                          \
} while (0)

__launch_bounds__(64, 1)
__global__ void crf_fb(const float* __restrict__ feats,
                       const float* __restrict__ masks,
                       const int* __restrict__ tags,
                       const float* __restrict__ trans,
                       float* __restrict__ out)
{
    __shared__ float tl[Td * Td];
    __shared__ __align__(16) float vls[2][Td];

    const int lane = threadIdx.x;
    const int b = blockIdx.x;

    for (int i = lane; i < Td * Td; i += 64) tl[i] = trans[i];
    __syncthreads();

    const size_t bS = (size_t)b * Sd;

    // ---- length from prefix mask ----
    float c = 0.f;
    for (int t = lane; t < Sd; t += 64) c += masks[bS + t];
#pragma unroll
    for (int off = 32; off; off >>= 1) c += __shfl_xor(c, off);
    int len = (int)(c + 0.5f);
    if (len < 1) len = 1;

    // ---- gold score ----
    float g = 0.f;
    for (int t = lane; t < len; t += 64) {
        const int tag  = tags[bS + t];
        const int prev = (t == 0) ? START_ : tags[bS + t - 1];
        g += feats[(bS + t) * Td + tag] + tl[tag * Td + prev];
    }
#pragma unroll
    for (int off = 32; off; off >>= 1) g += __shfl_xor(g, off);
    g += tl[STOP_ * Td + tags[bS + len - 1]];

    // ---- E row (fwd) and E^T row (bwd) per lane ----
    const bool vlane = (lane < Td);
    const bool frow_ok = (lane < NTAG);   // fwd rows 45..47 are exact sinks
    v2f E2[24], ET2[24];
#pragma unroll
    for (int q = 0; q < 24; ++q) {
        E2[q].x  = frow_ok ? __expf(tl[lane * Td + 2*q])     : 0.f;
        E2[q].y  = frow_ok ? __expf(tl[lane * Td + 2*q + 1]) : 0.f;
        ET2[q].x = vlane   ? __expf(tl[(2*q)   * Td + lane]) : 0.f;
        ET2[q].y = vlane   ? __expf(tl[(2*q+1) * Td + lane]) : 0.f;
    }
    const float Estart = E2[22].y;        // E[lane][START_], 45 = 2*22+1
    const float wstop  = vlane ? __expf(tl[STOP_ * Td + lane]) : 0.f;

    const int lidx = vlane ? lane : 0;
    const float* frow = feats + bS * Td;

    // ---- meet-in-the-middle split ----
    const int F  = (len + 1) >> 1;        // forward consumes times 0..F-1
    const int NB = len - F;               // backward matvec count (times len-1..F)
    const int TRIP = (F - 1) > NB ? (F - 1) : NB;

    // inits: fwd peel (time 0); bwd u=w with emission e_{len-1} folded in
    float vF = __expf(frow[lidx]) * Estart;                       // v_(0)
    float uW = wstop * __expf(frow[(size_t)(len - 1) * Td + lidx]);
    float uFin = wstop;                   // correct answer piece when NB==0
    int LF = 0, LB = 0;
    if (vlane) { vls[0][lane] = vF; vls[1][lane] = uW; }
    asm volatile("" ::: "memory");
    v4f rF[12], rU[12];
#pragma unroll
    for (int q = 0; q < 12; ++q) {
        rF[q] = ((const v4f*)vls[0])[q];
        rU[q] = ((const v4f*)vls[1])[q];
    }

    // ---- emission prefetch, depth 4 per chain ----
    // fwd superstep k consumes e_{k+1}; bwd superstep k consumes e_{len-2-k}
    float pf0F, pf1F, pf2F, pf3F, pf0U, pf1U, pf2U, pf3U;
    {
        int i;
        i = (1 < F) ? 1 : 0;              pf0F = frow[(size_t)i * Td + lidx];
        i = (2 < F) ? 2 : 0;              pf1F = frow[(size_t)i * Td + lidx];
        i = (3 < F) ? 3 : 0;              pf2F = frow[(size_t)i * Td + lidx];
        i = (4 < F) ? 4 : 0;              pf3F = frow[(size_t)i * Td + lidx];
        i = (0 < NB) ? (len - 2) : 0;     pf0U = frow[(size_t)i * Td + lidx];
        i = (1 < NB) ? (len - 3) : 0;     pf1U = frow[(size_t)i * Td + lidx];
        i = (2 < NB) ? (len - 4) : 0;     pf2U = frow[(size_t)i * Td + lidx];
        i = (3 < NB) ? (len - 5) : 0;     pf3U = frow[(size_t)i * Td + lidx];
    }

    int k = 0;
    while (k + 4 <= TRIP) {
        {
            const bool aF = (k < F - 1), aU = (k < NB);
            SUPERSTEP(pf0F, pf0U, aF, aU);
            const int tn = k + 4;
            pf0F = frow[(size_t)((tn + 1 < F) ? (tn + 1) : 0) * Td + lidx];
            pf0U = frow[(size_t)((tn < NB) ? (len - 2 - tn) : 0) * Td + lidx];
        }
        {
            const bool aF = (k + 1 < F - 1), aU = (k + 1 < NB);
            SUPERSTEP(pf1F, pf1U, aF, aU);
            const int tn = k + 5;
            pf1F = frow[(size_t)((tn + 1 < F) ? (tn + 1) : 0) * Td + lidx];
            pf1U = frow[(size_t)((tn < NB) ? (len - 2 - tn) : 0) * Td + lidx];
        }
        {
            const bool aF = (k + 2 < F - 1), aU = (k + 2 < NB);
            SUPERSTEP(pf2F, pf2U, aF, aU);
            const int tn = k + 6;
            pf2F = frow[(size_t)((tn + 1 < F) ? (tn + 1) : 0) * Td + lidx];
            pf2U = frow[(size_t)((tn < NB) ? (len - 2 - tn) : 0) * Td + lidx];
        }
        {
            const bool aF = (k + 3 < F - 1), aU = (k + 3 < NB);
            SUPERSTEP(pf3F, pf3U, aF, aU);
            const int tn = k + 7;
            pf3F = frow[(size_t)((tn + 1 < F) ? (tn + 1) : 0) * Td + lidx];
            pf3U = frow[(size_t)((tn < NB) ? (len - 2 - tn) : 0) * Td + lidx];
        }
        k += 4;
    }
    if (k < TRIP) { const bool aF = (k < F - 1), aU = (k < NB); SUPERSTEP(pf0F, pf0U, aF, aU); ++k; }
    if (k < TRIP) { const bool aF = (k < F - 1), aU = (k < NB); SUPERSTEP(pf1F, pf1U, aF, aU); ++k; }
    if (k < TRIP) { const bool aF = (k < F - 1), aU = (k < NB); SUPERSTEP(pf2F, pf2U, aF, aU); ++k; }

    // ---- combine: answer_exp * 2^-(LF+LB) = dot(uFin, rF) ----
    if (vlane) vls[1][lane] = uFin;
    asm volatile("" ::: "memory");
    float dot = 0.f;
#pragma unroll
    for (int q = 0; q < 12; ++q) {
        v4f ur = ((const v4f*)vls[1])[q];
        dot += ur.x * rF[q].x + ur.y * rF[q].y + ur.z * rF[q].z + ur.w * rF[q].w;
    }

    if (lane == 0) {
        const float ln2 = 0.6931471805599453f;
        out[b] = (float)(LF + LB) * ln2 + __logf(dot) - g;
    }
}

extern "C" void kernel_launch(void* const* d_in, const int* in_sizes, int n_in,
                              void* d_out, int out_size, void* d_ws, size_t ws_size,
                              hipStream_t stream) {
    const float* feats = (const float*)d_in[0];
    const float* masks = (const float*)d_in[1];
    const int*   tags  = (const int*)d_in[2];
    const float* trans = (const float*)d_in[3];
    float* outp = (float*)d_out;

    const int Bn = in_sizes[1] / Sd;     // B = 512
    crf_fb<<<dim3(Bn), dim3(64), 0, stream>>>(feats, masks, tags, trans, outp);
}